// Round 1
// 329.891 us; speedup vs baseline: 1.0234x; 1.0234x over previous
//
#include <hip/hip_runtime.h>
#include <stdint.h>

#define NL   12
#define PTOT 32936
#define LMB  32778
#define NCH  515           // ceil(PTOT/64) words of positivity bits
#define NCHP 520           // padded LDS words
#define NGRP 129           // ceil(NCH/4) 256-elem groups
#define BMW  (NGRP * 4)    // 516 bm words per row (interleaved ballot layout)
#define TPAD (NGRP * 256)  // 33024 padded table elems
#define NGPW 4             // groups per wave in sample kernel

typedef float vf4 __attribute__((ext_vector_type(4)));

__device__ __constant__ int c_base[NL] = {0,86,653,1701,3230,5240,7731,10703,14156,18090,22505,27401};

__device__ __forceinline__ uint64_t ext(const uint64_t* P, uint32_t off) {
  uint32_t w = off >> 6, s = off & 63;
  uint64_t lo = P[w], hi = P[w + 1];
  return s ? ((lo >> s) | (hi << (64 - s))) : lo;
}

__device__ __forceinline__ uint64_t rbit(uint64_t r0, uint64_t r1, uint64_t r2, uint32_t idx) {
  uint64_t w = idx < 64 ? r0 : (idx < 128 ? r1 : r2);
  return (w >> (idx & 63)) & 1ull;
}

__device__ __forceinline__ void orAt(uint64_t& r0, uint64_t& r1, uint64_t& r2,
                                     uint64_t val, uint32_t pos) {
  uint32_t w = pos >> 6, s = pos & 63;
  uint64_t lo = val << s;
  uint64_t hi = s ? (val >> (64 - s)) : 0ull;
  if (w == 0) { r0 |= lo; r1 |= hi; }
  else if (w == 1) { r1 |= lo; r2 |= hi; }
  else { r2 |= lo; }
}

__device__ __forceinline__ void maskLen(uint32_t len, uint64_t& m0, uint64_t& m1, uint64_t& m2) {
  m0 = (len >= 64) ? ~0ull : ((1ull << len) - 1ull);
  m1 = (len <= 64) ? 0ull : ((len >= 128) ? ~0ull : ((1ull << (len - 64)) - 1ull));
  m2 = (len <= 128) ? 0ull : ((1ull << (len - 128)) - 1ull);
}

__device__ __forceinline__ uint32_t ext12(uint64_t O0, uint64_t O1, uint64_t O2, uint32_t pos) {
  uint32_t w = pos >> 6, s = pos & 63;
  uint64_t lo = (w == 0) ? O0 : ((w == 1) ? O1 : O2);
  uint64_t hi = (w == 0) ? O1 : ((w == 1) ? O2 : 0ull);
  uint64_t v = s ? ((lo >> s) | (hi << (64 - s))) : lo;
  return (uint32_t)v & 0xFFFu;
}

// spread 16 bits to every 4th bit of a 64-bit word
__device__ __forceinline__ uint64_t spread4(uint64_t x) {
  x = (x | (x << 24)) & 0x000000FF000000FFull;
  x = (x | (x << 12)) & 0x000F000F000F000Full;
  x = (x | (x << 6))  & 0x0303030303030303ull;
  x = (x | (x << 3))  & 0x1111111111111111ull;
  return x;
}

// Per-param (prob', window) SoA tables + packed (outv|inv<<8) vertex table.
__global__ void init_tables(const float* __restrict__ sp, float* __restrict__ pr,
                            float* __restrict__ wd, unsigned short* __restrict__ vtx) {
  int p = blockIdx.x * blockDim.x + threadIdx.x;
  if (p >= TPAD) return;
  if (p < PTOT) {
    float x = sp[p];
    float s = 1.0f / (1.0f + expf(-x));                 // sigmoid, fp32
    float w = __fmul_rn(s, __fsub_rn(1.0f, s));         // window = p*(1-p)
    float pv = __fadd_rn(__fmul_rn(w, s), __fmul_rn(__fsub_rn(1.0f, w), s));
    pr[p] = pv; wd[p] = w;
    int outv, inv;
    if (p >= LMB) { outv = p - LMB; inv = outv; }
    else {
      int L = 0;
#pragma unroll
      for (int i = 1; i < NL; ++i) if (p >= c_base[i]) L = i;
      int Vq  = 2 + 13 * L;
      int off = p - c_base[L];
      int nq  = 36 * Vq;
      if (off < nq) { int g = off / Vq; inv = off - g * Vq; outv = Vq + (g % 12); }
      else          { outv = Vq + 12; inv = off - nq; }
    }
    vtx[p] = (unsigned short)(outv | (inv << 8));
  } else {
    pr[p] = 0.0f; wd[p] = 1.0f; vtx[p] = 0;
  }
}

// ---- Kernel A: float4 streaming: masks -> out, interleaved pos bits -> bm
__global__ __launch_bounds__(256) void sample_kernel(const float* __restrict__ unif,
                                                     const vf4* __restrict__ pr4,
                                                     const vf4* __restrict__ wd4,
                                                     float* __restrict__ out,
                                                     uint64_t* __restrict__ bm) {
  const int lane = threadIdx.x & 63;
  const int wv   = threadIdx.x >> 6;
  const int row  = blockIdx.y;
  const vf4* up4 = (const vf4*)(unif + (size_t)row * PTOT);
  vf4*       op4 = (vf4*)(out + (size_t)row * PTOT);
  uint64_t*  bp  = bm + (size_t)row * BMW;
  const int g0 = (blockIdx.x * 4 + wv) * NGPW;
#pragma unroll
  for (int k = 0; k < NGPW; ++k) {
    int G = g0 + k;
    if (G >= NGRP) break;
    int e4 = G * 64 + lane;                 // float4 index within row
    bool inb = e4 < (PTOT / 4);             // 8234
    vf4 u = inb ? __builtin_nontemporal_load(&up4[e4]) : (vf4){0.f, 0.f, 0.f, 0.f};
    vf4 p = pr4[e4];                        // padded tables: always safe
    vf4 w = wd4[e4];
    float m0 = __fadd_rn(__fdiv_rn(__fsub_rn(p.x, u.x), w.x), 0.5f);
    float m1 = __fadd_rn(__fdiv_rn(__fsub_rn(p.y, u.y), w.y), 0.5f);
    float m2 = __fadd_rn(__fdiv_rn(__fsub_rn(p.z, u.z), w.z), 0.5f);
    float m3 = __fadd_rn(__fdiv_rn(__fsub_rn(p.w, u.w), w.w), 0.5f);
    if (inb) {
      vf4 o;
      o.x = fminf(fmaxf(m0, 0.0f), 1.0f);
      o.y = fminf(fmaxf(m1, 0.0f), 1.0f);
      o.z = fminf(fmaxf(m2, 0.0f), 1.0f);
      o.w = fminf(fmaxf(m3, 0.0f), 1.0f);
      __builtin_nontemporal_store(o, &op4[e4]);
    }
    uint64_t b0 = __ballot(inb && (m0 > 0.0f));
    uint64_t b1 = __ballot(inb && (m1 > 0.0f));
    uint64_t b2 = __ballot(inb && (m2 > 0.0f));
    uint64_t b3 = __ballot(inb && (m3 > 0.0f));
    if (lane < 4) {
      uint64_t v = (lane == 0) ? b0 : (lane == 1) ? b1 : (lane == 2) ? b2 : b3;
      bp[G * 4 + lane] = v;
    }
  }
}

// ---- Kernel B: per-row graph prune -----------------------------------------
// Key identity: the backward-liveness set O satisfies O ⊆ R (every bit OR'd
// into O is AND-masked by R), so
//   * phase 3 can read raw sPos and AND in R on the fly (no materialized
//     forward-pruned copy sPos2 needed; the out-vertex R factor is implied
//     by the O-guard), and
//   * the final per-edge keep is R[out]&R[in]&O[out]&O[in]
//     = live[out]&live[in] with live = R∩O  -> ONE rbit pass, not two.
__global__ __launch_bounds__(256) void prune_kernel(const uint64_t* __restrict__ bm,
                                                    const unsigned short* __restrict__ vtx,
                                                    float* __restrict__ out) {
  __shared__ uint64_t sPos[NCHP];   // raw positivity bits (later: z words)
  __shared__ uint32_t sL[6];        // live = R & O
  __shared__ int sQn;
  __shared__ unsigned short sQ[NCH];

  const int tid  = threadIdx.x;
  const int lane = tid & 63;
  const int wv   = tid >> 6;
  const int row  = blockIdx.x;
  const uint64_t* bp = bm  + (size_t)row * BMW;
  float*           op = out + (size_t)row * PTOT;

  if (tid == 0) sQn = 0;
  // ---- load + deinterleave ballots into contiguous-bit words -------------
  for (int G = tid; G < NGRP; G += 256) {
    const uint64_t* gp = bp + 4 * G;
    uint64_t b0 = gp[0], b1 = gp[1], b2 = gp[2], b3 = gp[3];
#pragma unroll
    for (int q = 0; q < 4; ++q) {
      uint64_t v = spread4((b0 >> (16 * q)) & 0xFFFFull)
                 | (spread4((b1 >> (16 * q)) & 0xFFFFull) << 1)
                 | (spread4((b2 >> (16 * q)) & 0xFFFFull) << 2)
                 | (spread4((b3 >> (16 * q)) & 0xFFFFull) << 3);
      sPos[4 * G + q] = v;
    }
  }
  for (int w = BMW + tid; w < NCHP; w += 256) sPos[w] = 0ull;
  __syncthreads();

  // ---- Phases 2+3 fused on wave 0: forward R, then backward O (R kept in
  //      registers; on-the-fly R-masking replaces the sPos2 pass) ----------
  if (tid < 64) {
    uint64_t R0 = 3ull, R1 = 0ull, R2 = 0ull;
    const int g = lane;
#pragma unroll
    for (int L = 0; L < NL; ++L) {
      const int Vq = 2 + 13 * L;
      const int b  = c_base[L];
      bool pred = false;
      if (g < 36) {
        uint32_t off = (uint32_t)(b + g * Vq);
        uint64_t e0 = ext(sPos, off), e1 = ext(sPos, off + 64), e2 = ext(sPos, off + 128);
        pred = ((e0 & R0) | (e1 & R1) | (e2 & R2)) != 0ull;
      }
      uint64_t bal = __ballot(pred);
      uint64_t ar  = bal & (bal >> 12) & (bal >> 24) & 0xFFFull;
      orAt(R0, R1, R2, ar, (uint32_t)Vq);
      const int Vm = Vq + 12;
      uint32_t offm = (uint32_t)(b + 36 * Vq);
      uint64_t e0 = ext(sPos, offm), e1 = ext(sPos, offm + 64), e2 = ext(sPos, offm + 128);
      uint64_t mr = (((e0 & R0) | (e1 & R1) | (e2 & R2)) != 0ull) ? 1ull : 0ull;
      orAt(R0, R1, R2, mr, (uint32_t)Vm);
    }

    // backward liveness with on-the-fly R-masking (pos2 == pos & R[in], and
    // the out-vertex factor is 1 inside every O-guard since O ⊆ R)
    uint64_t O0 = ext(sPos, LMB)       & R0;
    uint64_t O1 = ext(sPos, LMB + 64)  & R1;
    uint64_t O2 = ext(sPos, LMB + 128) & ((1ull << 30) - 1ull) & R2;
    const int hg = g % 12;
#pragma unroll
    for (int L = NL - 1; L >= 0; --L) {
      const int Vq = 2 + 13 * L, Vm = Vq + 12;
      const int b  = c_base[L];
      if (rbit(O0, O1, O2, (uint32_t)Vm)) {
        uint64_t m0, m1, m2; maskLen((uint32_t)Vm, m0, m1, m2);
        uint32_t offm = (uint32_t)(b + 36 * Vq);
        O0 |= ext(sPos, offm)       & R0 & m0;
        O1 |= ext(sPos, offm + 64)  & R1 & m1;
        O2 |= ext(sPos, offm + 128) & R2 & m2;
      }
      uint32_t h12 = ext12(O0, O1, O2, (uint32_t)Vq);
      uint64_t q0, q1, q2; maskLen((uint32_t)Vq, q0, q1, q2);
      uint64_t c0 = 0ull, c1 = 0ull, c2 = 0ull;
      if (g < 36 && ((h12 >> hg) & 1u)) {
        uint32_t off = (uint32_t)(b + g * Vq);
        c0 = ext(sPos, off)       & R0 & q0;
        c1 = ext(sPos, off + 64)  & R1 & q1;
        c2 = ext(sPos, off + 128) & R2 & q2;
      }
#pragma unroll
      for (int d = 32; d; d >>= 1) {
        c0 |= __shfl_xor((unsigned long long)c0, d);
        c1 |= __shfl_xor((unsigned long long)c1, d);
        c2 |= __shfl_xor((unsigned long long)c2, d);
      }
      O0 |= c0; O1 |= c1; O2 |= c2;
    }
    if (lane == 0) {
      uint64_t l0 = R0 & O0, l1 = R1 & O1, l2 = R2 & O2;
      sL[0] = (uint32_t)l0; sL[1] = (uint32_t)(l0 >> 32);
      sL[2] = (uint32_t)l1; sL[3] = (uint32_t)(l1 >> 32);
      sL[4] = (uint32_t)l2; sL[5] = (uint32_t)(l2 >> 32);
    }
  }
  __syncthreads();

  // ---- Single combined keep pass: z-words + queue -------------------------
  {
    uint64_t l0 = ((uint64_t)sL[1] << 32) | sL[0];
    uint64_t l1 = ((uint64_t)sL[3] << 32) | sL[2];
    uint64_t l2 = ((uint64_t)sL[5] << 32) | sL[4];
    const uint32_t* vt32 = (const uint32_t*)vtx;
    for (int w = tid; w < NCH; w += 256) {
      uint64_t pm = sPos[w];
      if (!pm) continue;
      const uint32_t* vp = vt32 + w * 32;
      uint64_t keep = 0ull;
#pragma unroll 8
      for (int j = 0; j < 32; ++j) {
        uint32_t e = vp[j];
        uint64_t k0 = rbit(l0, l1, l2, e & 0xFFu)         & rbit(l0, l1, l2, (e >> 8) & 0xFFu);
        uint64_t k1 = rbit(l0, l1, l2, (e >> 16) & 0xFFu) & rbit(l0, l1, l2, e >> 24);
        keep |= (k0 << (2 * j)) | (k1 << (2 * j + 1));
      }
      uint64_t z = pm & ~keep;          // was >0 but pruned -> must write 0
      if (z) {
        sPos[w] = z;
        int k = atomicAdd(&sQn, 1);
        sQ[k] = (unsigned short)w;
      }
    }
  }
  __syncthreads();

  // ---- coalesced lane-predicated zero stores ------------------------------
  {
    const int qn = sQn;
    for (int k = wv; k < qn; k += 4) {
      int w = sQ[k];
      uint64_t z = sPos[w];
      if ((z >> lane) & 1ull) op[w * 64 + lane] = 0.0f;
    }
  }
}

extern "C" void kernel_launch(void* const* d_in, const int* in_sizes, int n_in,
                              void* d_out, int out_size, void* d_ws, size_t ws_size,
                              hipStream_t stream) {
  const float* sp   = (const float*)d_in[0];
  const float* unif = (const float*)d_in[1];
  float* out = (float*)d_out;
  char* ws = (char*)d_ws;
  float* pr = (float*)ws;                                  // 132096 B
  float* wd = (float*)(ws + 132096);                       // 132096 B
  unsigned short* vtx = (unsigned short*)(ws + 264192);    //  66048 B
  uint64_t* bm = (uint64_t*)(ws + 330240);                 // 1024*516*8 B
  int bz = in_sizes[1] / PTOT;   // 1024

  init_tables<<<dim3(TPAD / 256), dim3(256), 0, stream>>>(sp, pr, wd, vtx);
  // 4 waves/block x NGPW groups/wave = 16 groups/block; 9 blocks cover 129
  sample_kernel<<<dim3((NGRP + 4 * NGPW - 1) / (4 * NGPW), bz), dim3(256), 0, stream>>>(
      unif, (const vf4*)pr, (const vf4*)wd, out, bm);
  prune_kernel<<<dim3(bz), dim3(256), 0, stream>>>(bm, vtx, out);
}

// Round 2
// 316.006 us; speedup vs baseline: 1.0684x; 1.0439x over previous
//
#include <hip/hip_runtime.h>
#include <stdint.h>

#define NL   12
#define PTOT 32936
#define LMB  32778
#define NCH  515           // ceil(PTOT/64) words of positivity bits
#define NCHP 520           // padded LDS words
#define NGRP 129           // ceil(NCH/4) 256-elem groups
#define BMW  (NGRP * 4)    // 516 bm words per row (interleaved ballot layout)
#define TPAD (NGRP * 256)  // 33024 padded table elems
#define NGPW 4             // groups per wave in sample kernel
#define NSEG 445           // 12 layers * 37 segments + 1 LM segment

typedef float vf4 __attribute__((ext_vector_type(4)));

__device__ __constant__ int c_base[NL] = {0,86,653,1701,3230,5240,7731,10703,14156,18090,22505,27401};

__device__ __forceinline__ uint64_t ext(const uint64_t* P, uint32_t off) {
  uint32_t w = off >> 6, s = off & 63;
  uint64_t lo = P[w], hi = P[w + 1];
  return s ? ((lo >> s) | (hi << (64 - s))) : lo;
}

__device__ __forceinline__ uint64_t rbit(uint64_t r0, uint64_t r1, uint64_t r2, uint32_t idx) {
  uint64_t w = idx < 64 ? r0 : (idx < 128 ? r1 : r2);
  return (w >> (idx & 63)) & 1ull;
}

// register-resident ext over the 158-bit live vector (l3 == 0 implied)
__device__ __forceinline__ uint64_t rext(uint64_t a0, uint64_t a1, uint64_t a2, uint32_t off) {
  uint32_t w = off >> 6, s = off & 63;
  uint64_t lo = (w == 0) ? a0 : ((w == 1) ? a1 : ((w == 2) ? a2 : 0ull));
  uint64_t hi = (w == 0) ? a1 : ((w == 1) ? a2 : 0ull);
  return s ? ((lo >> s) | (hi << (64 - s))) : lo;
}

__device__ __forceinline__ void orAt(uint64_t& r0, uint64_t& r1, uint64_t& r2,
                                     uint64_t val, uint32_t pos) {
  uint32_t w = pos >> 6, s = pos & 63;
  uint64_t lo = val << s;
  uint64_t hi = s ? (val >> (64 - s)) : 0ull;
  if (w == 0) { r0 |= lo; r1 |= hi; }
  else if (w == 1) { r1 |= lo; r2 |= hi; }
  else { r2 |= lo; }
}

__device__ __forceinline__ void maskLen(uint32_t len, uint64_t& m0, uint64_t& m1, uint64_t& m2) {
  m0 = (len >= 64) ? ~0ull : ((1ull << len) - 1ull);
  m1 = (len <= 64) ? 0ull : ((len >= 128) ? ~0ull : ((1ull << (len - 64)) - 1ull));
  m2 = (len <= 128) ? 0ull : ((1ull << (len - 128)) - 1ull);
}

__device__ __forceinline__ uint32_t ext12(uint64_t O0, uint64_t O1, uint64_t O2, uint32_t pos) {
  uint32_t w = pos >> 6, s = pos & 63;
  uint64_t lo = (w == 0) ? O0 : ((w == 1) ? O1 : O2);
  uint64_t hi = (w == 0) ? O1 : ((w == 1) ? O2 : 0ull);
  uint64_t v = s ? ((lo >> s) | (hi << (64 - s))) : lo;
  return (uint32_t)v & 0xFFFu;
}

// spread 16 bits to every 4th bit of a 64-bit word
__device__ __forceinline__ uint64_t spread4(uint64_t x) {
  x = (x | (x << 24)) & 0x000000FF000000FFull;
  x = (x | (x << 12)) & 0x000F000F000F000Full;
  x = (x | (x << 6))  & 0x0303030303030303ull;
  x = (x | (x << 3))  & 0x1111111111111111ull;
  return x;
}

// Per-param (prob', window) SoA tables (vtx table no longer needed: the keep
// mask is now built per-segment from the live bitvector, not per-edge).
__global__ void init_tables(const float* __restrict__ sp, float* __restrict__ pr,
                            float* __restrict__ wd) {
  int p = blockIdx.x * blockDim.x + threadIdx.x;
  if (p >= TPAD) return;
  if (p < PTOT) {
    float x = sp[p];
    float s = 1.0f / (1.0f + expf(-x));                 // sigmoid, fp32
    float w = __fmul_rn(s, __fsub_rn(1.0f, s));         // window = p*(1-p)
    float pv = __fadd_rn(__fmul_rn(w, s), __fmul_rn(__fsub_rn(1.0f, w), s));
    pr[p] = pv; wd[p] = w;
  } else {
    pr[p] = 0.0f; wd[p] = 1.0f;
  }
}

// ---- Kernel A: float4 streaming: masks -> out, interleaved pos bits -> bm
__global__ __launch_bounds__(256) void sample_kernel(const float* __restrict__ unif,
                                                     const vf4* __restrict__ pr4,
                                                     const vf4* __restrict__ wd4,
                                                     float* __restrict__ out,
                                                     uint64_t* __restrict__ bm) {
  const int lane = threadIdx.x & 63;
  const int wv   = threadIdx.x >> 6;
  const int row  = blockIdx.y;
  const vf4* up4 = (const vf4*)(unif + (size_t)row * PTOT);
  vf4*       op4 = (vf4*)(out + (size_t)row * PTOT);
  uint64_t*  bp  = bm + (size_t)row * BMW;
  const int g0 = (blockIdx.x * 4 + wv) * NGPW;
#pragma unroll
  for (int k = 0; k < NGPW; ++k) {
    int G = g0 + k;
    if (G >= NGRP) break;
    int e4 = G * 64 + lane;                 // float4 index within row
    bool inb = e4 < (PTOT / 4);             // 8234
    vf4 u = inb ? __builtin_nontemporal_load(&up4[e4]) : (vf4){0.f, 0.f, 0.f, 0.f};
    vf4 p = pr4[e4];                        // padded tables: always safe
    vf4 w = wd4[e4];
    float m0 = __fadd_rn(__fdiv_rn(__fsub_rn(p.x, u.x), w.x), 0.5f);
    float m1 = __fadd_rn(__fdiv_rn(__fsub_rn(p.y, u.y), w.y), 0.5f);
    float m2 = __fadd_rn(__fdiv_rn(__fsub_rn(p.z, u.z), w.z), 0.5f);
    float m3 = __fadd_rn(__fdiv_rn(__fsub_rn(p.w, u.w), w.w), 0.5f);
    if (inb) {
      vf4 o;
      o.x = fminf(fmaxf(m0, 0.0f), 1.0f);
      o.y = fminf(fmaxf(m1, 0.0f), 1.0f);
      o.z = fminf(fmaxf(m2, 0.0f), 1.0f);
      o.w = fminf(fmaxf(m3, 0.0f), 1.0f);
      __builtin_nontemporal_store(o, &op4[e4]);
    }
    uint64_t b0 = __ballot(inb && (m0 > 0.0f));
    uint64_t b1 = __ballot(inb && (m1 > 0.0f));
    uint64_t b2 = __ballot(inb && (m2 > 0.0f));
    uint64_t b3 = __ballot(inb && (m3 > 0.0f));
    if (lane < 4) {
      uint64_t v = (lane == 0) ? b0 : (lane == 1) ? b1 : (lane == 2) ? b2 : b3;
      bp[G * 4 + lane] = v;
    }
  }
}

// ---- Kernel B: per-row graph prune -----------------------------------------
// live = R & O (O computed with on-the-fly R-masking; O ⊆ R).
// Final per-edge keep = live[out] & live[in].
// KEY: the edge->vertex map is piecewise sequential. In every segment
// (one head-row of a QKV block: out const = Vq+(g%12), in = 0..Vq-1;
//  one mm block: out const = Vq+12, in = 0..Vm-1;
//  the LM tail: keep[i] = live[i]),
// the keep bits are exactly:  out_live ? live[0..len) : 0  — a shifted
// window of the 158-bit live vector. So the whole 515-word keep bitvector
// is built with ~960 word-granular atomicOr's over 445 segments instead of
// 515*32 per-edge bit extracts. The vtx table is gone.
__global__ __launch_bounds__(256) void prune_kernel(const uint64_t* __restrict__ bm,
                                                    float* __restrict__ out) {
  __shared__ uint64_t sPos[NCHP];    // raw positivity bits (later: z words)
  __shared__ uint64_t sKeep[NCHP];   // keep bitvector
  __shared__ uint64_t sLv[4];        // live = R & O (padded, sLv[3]=0)
  __shared__ int sQn;
  __shared__ unsigned short sQ[NCH];

  const int tid  = threadIdx.x;
  const int lane = tid & 63;
  const int wv   = tid >> 6;
  const int row  = blockIdx.x;
  const uint64_t* bp = bm  + (size_t)row * BMW;
  float*           op = out + (size_t)row * PTOT;

  if (tid == 0) sQn = 0;
  // ---- load + deinterleave ballots into contiguous-bit words; zero sKeep --
  for (int G = tid; G < NGRP; G += 256) {
    const uint64_t* gp = bp + 4 * G;
    uint64_t b0 = gp[0], b1 = gp[1], b2 = gp[2], b3 = gp[3];
#pragma unroll
    for (int q = 0; q < 4; ++q) {
      uint64_t v = spread4((b0 >> (16 * q)) & 0xFFFFull)
                 | (spread4((b1 >> (16 * q)) & 0xFFFFull) << 1)
                 | (spread4((b2 >> (16 * q)) & 0xFFFFull) << 2)
                 | (spread4((b3 >> (16 * q)) & 0xFFFFull) << 3);
      sPos[4 * G + q] = v;
    }
  }
  for (int w = BMW + tid; w < NCHP; w += 256) sPos[w] = 0ull;
  for (int w = tid; w < NCHP; w += 256) sKeep[w] = 0ull;
  __syncthreads();

  // ---- Phases 2+3 fused on wave 0: forward R, then backward O -------------
  if (tid < 64) {
    uint64_t R0 = 3ull, R1 = 0ull, R2 = 0ull;
    const int g = lane;
#pragma unroll
    for (int L = 0; L < NL; ++L) {
      const int Vq = 2 + 13 * L;
      const int b  = c_base[L];
      bool pred = false;
      if (g < 36) {
        uint32_t off = (uint32_t)(b + g * Vq);
        uint64_t e0 = ext(sPos, off), e1 = ext(sPos, off + 64), e2 = ext(sPos, off + 128);
        pred = ((e0 & R0) | (e1 & R1) | (e2 & R2)) != 0ull;
      }
      uint64_t bal = __ballot(pred);
      uint64_t ar  = bal & (bal >> 12) & (bal >> 24) & 0xFFFull;
      orAt(R0, R1, R2, ar, (uint32_t)Vq);
      const int Vm = Vq + 12;
      uint32_t offm = (uint32_t)(b + 36 * Vq);
      uint64_t e0 = ext(sPos, offm), e1 = ext(sPos, offm + 64), e2 = ext(sPos, offm + 128);
      uint64_t mr = (((e0 & R0) | (e1 & R1) | (e2 & R2)) != 0ull) ? 1ull : 0ull;
      orAt(R0, R1, R2, mr, (uint32_t)Vm);
    }

    // backward liveness with on-the-fly R-masking (O ⊆ R)
    uint64_t O0 = ext(sPos, LMB)       & R0;
    uint64_t O1 = ext(sPos, LMB + 64)  & R1;
    uint64_t O2 = ext(sPos, LMB + 128) & ((1ull << 30) - 1ull) & R2;
    const int hg = g % 12;
#pragma unroll
    for (int L = NL - 1; L >= 0; --L) {
      const int Vq = 2 + 13 * L, Vm = Vq + 12;
      const int b  = c_base[L];
      if (rbit(O0, O1, O2, (uint32_t)Vm)) {
        uint64_t m0, m1, m2; maskLen((uint32_t)Vm, m0, m1, m2);
        uint32_t offm = (uint32_t)(b + 36 * Vq);
        O0 |= ext(sPos, offm)       & R0 & m0;
        O1 |= ext(sPos, offm + 64)  & R1 & m1;
        O2 |= ext(sPos, offm + 128) & R2 & m2;
      }
      uint32_t h12 = ext12(O0, O1, O2, (uint32_t)Vq);
      uint64_t q0, q1, q2; maskLen((uint32_t)Vq, q0, q1, q2);
      uint64_t c0 = 0ull, c1 = 0ull, c2 = 0ull;
      if (g < 36 && ((h12 >> hg) & 1u)) {
        uint32_t off = (uint32_t)(b + g * Vq);
        c0 = ext(sPos, off)       & R0 & q0;
        c1 = ext(sPos, off + 64)  & R1 & q1;
        c2 = ext(sPos, off + 128) & R2 & q2;
      }
#pragma unroll
      for (int d = 32; d; d >>= 1) {
        c0 |= __shfl_xor((unsigned long long)c0, d);
        c1 |= __shfl_xor((unsigned long long)c1, d);
        c2 |= __shfl_xor((unsigned long long)c2, d);
      }
      O0 |= c0; O1 |= c1; O2 |= c2;
    }
    if (lane == 0) {
      sLv[0] = R0 & O0; sLv[1] = R1 & O1; sLv[2] = R2 & O2; sLv[3] = 0ull;
    }
  }
  __syncthreads();

  // ---- Segment pass: build keep bitvector via shifted live windows --------
  {
    const uint64_t l0 = sLv[0], l1 = sLv[1], l2 = sLv[2];
    for (int s = tid; s < NSEG; s += 256) {
      uint32_t p0, len;
      bool olive;
      if (s == NSEG - 1) {               // LM tail: keep[i] = live[i]
        p0 = LMB; len = 158; olive = true;
      } else {
        int L = s / 37, j = s - L * 37;
        int Vq = 2 + 13 * L, b = c_base[L];
        if (j < 36) { p0 = (uint32_t)(b + j * Vq); len = (uint32_t)Vq;
                      olive = rbit(l0, l1, l2, (uint32_t)(Vq + (j % 12))) != 0ull; }
        else        { p0 = (uint32_t)(b + 36 * Vq); len = (uint32_t)(Vq + 12);
                      olive = rbit(l0, l1, l2, (uint32_t)(Vq + 12)) != 0ull; }
      }
      if (!olive) continue;
      uint32_t w0 = p0 >> 6, s0 = p0 & 63;
      uint64_t first = l0;
      if (len < 64) first &= (1ull << len) - 1ull;
      atomicOr((unsigned long long*)&sKeep[w0], (unsigned long long)(first << s0));
      uint32_t done = 64 - s0;
      uint32_t w = w0 + 1;
      while (done < len) {
        uint64_t v = rext(l0, l1, l2, done);
        uint32_t rem = len - done;
        if (rem < 64) v &= (1ull << rem) - 1ull;
        atomicOr((unsigned long long*)&sKeep[w], (unsigned long long)v);
        done += 64; ++w;
      }
    }
  }
  __syncthreads();

  // ---- z-words + queue -----------------------------------------------------
  for (int w = tid; w < NCH; w += 256) {
    uint64_t pm = sPos[w];
    if (!pm) continue;
    uint64_t z = pm & ~sKeep[w];        // was >0 but pruned -> must write 0
    if (z) {
      sPos[w] = z;
      int k = atomicAdd(&sQn, 1);
      sQ[k] = (unsigned short)w;
    }
  }
  __syncthreads();

  // ---- coalesced lane-predicated zero stores ------------------------------
  {
    const int qn = sQn;
    for (int k = wv; k < qn; k += 4) {
      int w = sQ[k];
      uint64_t z = sPos[w];
      if ((z >> lane) & 1ull) op[w * 64 + lane] = 0.0f;
    }
  }
}

extern "C" void kernel_launch(void* const* d_in, const int* in_sizes, int n_in,
                              void* d_out, int out_size, void* d_ws, size_t ws_size,
                              hipStream_t stream) {
  const float* sp   = (const float*)d_in[0];
  const float* unif = (const float*)d_in[1];
  float* out = (float*)d_out;
  char* ws = (char*)d_ws;
  float* pr = (float*)ws;                                  // 132096 B
  float* wd = (float*)(ws + 132096);                       // 132096 B
  uint64_t* bm = (uint64_t*)(ws + 264192);                 // 1024*516*8 B
  int bz = in_sizes[1] / PTOT;   // 1024

  init_tables<<<dim3(TPAD / 256), dim3(256), 0, stream>>>(sp, pr, wd);
  // 4 waves/block x NGPW groups/wave = 16 groups/block; 9 blocks cover 129
  sample_kernel<<<dim3((NGRP + 4 * NGPW - 1) / (4 * NGPW), bz), dim3(256), 0, stream>>>(
      unif, (const vf4*)pr, (const vf4*)wd, out, bm);
  prune_kernel<<<dim3(bz), dim3(256), 0, stream>>>(bm, out);
}

// Round 3
// 307.594 us; speedup vs baseline: 1.0976x; 1.0273x over previous
//
#include <hip/hip_runtime.h>
#include <stdint.h>

#define NL   12
#define PTOT 32936
#define LMB  32778
#define NCH  515           // ceil(PTOT/64) words of positivity bits
#define NCHP 520           // padded LDS words
#define NGRP 129           // ceil(NCH/4) 256-elem groups (64 float4 / group)
#define BMW  (NGRP * 4)    // 516 ballot words (interleaved layout)
#define TPAD (NGRP * 256)  // 33024 padded table elems
#define NSEG 445           // 12 layers * 37 segments + 1 LM segment

typedef float vf4 __attribute__((ext_vector_type(4)));

__device__ __constant__ int c_base[NL] = {0,86,653,1701,3230,5240,7731,10703,14156,18090,22505,27401};

__device__ __forceinline__ uint64_t ext(const uint64_t* P, uint32_t off) {
  uint32_t w = off >> 6, s = off & 63;
  uint64_t lo = P[w], hi = P[w + 1];
  return s ? ((lo >> s) | (hi << (64 - s))) : lo;
}

__device__ __forceinline__ uint64_t rbit(uint64_t r0, uint64_t r1, uint64_t r2, uint32_t idx) {
  uint64_t w = idx < 64 ? r0 : (idx < 128 ? r1 : r2);
  return (w >> (idx & 63)) & 1ull;
}

// register-resident ext over the 158-bit live vector (bits >=192 implied 0)
__device__ __forceinline__ uint64_t rext(uint64_t a0, uint64_t a1, uint64_t a2, uint32_t off) {
  uint32_t w = off >> 6, s = off & 63;
  uint64_t lo = (w == 0) ? a0 : ((w == 1) ? a1 : ((w == 2) ? a2 : 0ull));
  uint64_t hi = (w == 0) ? a1 : ((w == 1) ? a2 : 0ull);
  return s ? ((lo >> s) | (hi << (64 - s))) : lo;
}

__device__ __forceinline__ void orAt(uint64_t& r0, uint64_t& r1, uint64_t& r2,
                                     uint64_t val, uint32_t pos) {
  uint32_t w = pos >> 6, s = pos & 63;
  uint64_t lo = val << s;
  uint64_t hi = s ? (val >> (64 - s)) : 0ull;
  if (w == 0) { r0 |= lo; r1 |= hi; }
  else if (w == 1) { r1 |= lo; r2 |= hi; }
  else { r2 |= lo; }
}

__device__ __forceinline__ void maskLen(uint32_t len, uint64_t& m0, uint64_t& m1, uint64_t& m2) {
  m0 = (len >= 64) ? ~0ull : ((1ull << len) - 1ull);
  m1 = (len <= 64) ? 0ull : ((len >= 128) ? ~0ull : ((1ull << (len - 64)) - 1ull));
  m2 = (len <= 128) ? 0ull : ((1ull << (len - 128)) - 1ull);
}

__device__ __forceinline__ uint32_t ext12(uint64_t O0, uint64_t O1, uint64_t O2, uint32_t pos) {
  uint32_t w = pos >> 6, s = pos & 63;
  uint64_t lo = (w == 0) ? O0 : ((w == 1) ? O1 : O2);
  uint64_t hi = (w == 0) ? O1 : ((w == 1) ? O2 : 0ull);
  uint64_t v = s ? ((lo >> s) | (hi << (64 - s))) : lo;
  return (uint32_t)v & 0xFFFu;
}

// spread 16 bits to every 4th bit of a 64-bit word
__device__ __forceinline__ uint64_t spread4(uint64_t x) {
  x = (x | (x << 24)) & 0x000000FF000000FFull;
  x = (x | (x << 12)) & 0x000F000F000F000Full;
  x = (x | (x << 6))  & 0x0303030303030303ull;
  x = (x | (x << 3))  & 0x1111111111111111ull;
  return x;
}

// Per-param (prob', window) SoA tables.
__global__ void init_tables(const float* __restrict__ sp, float* __restrict__ pr,
                            float* __restrict__ wd) {
  int p = blockIdx.x * blockDim.x + threadIdx.x;
  if (p >= TPAD) return;
  if (p < PTOT) {
    float x = sp[p];
    float s = 1.0f / (1.0f + expf(-x));                 // sigmoid, fp32
    float w = __fmul_rn(s, __fsub_rn(1.0f, s));         // window = p*(1-p)
    float pv = __fadd_rn(__fmul_rn(w, s), __fmul_rn(__fsub_rn(1.0f, w), s));
    pr[p] = pv; wd[p] = w;
  } else {
    pr[p] = 0.0f; wd[p] = 1.0f;
  }
}

// ---- Fused kernel: one block per row ---------------------------------------
// Phase A : stream unif -> masks -> out (nontemporal), ballot positivity
//           bits straight into LDS (no global bm round-trip, no 2nd launch).
// Phase B : deinterleave ballots into contiguous-bit words (spread4).
// Phase C : wave 0: forward reachability R then backward liveness O with
//           on-the-fly R-masking (O ⊆ R); live = R & O.
// Phase D : per-segment shifted-window keep build (edge map is piecewise
//           sequential: keep[seg] = out_live ? live[0..len) : 0).
// Phase E : z-words + queue, coalesced lane-predicated zero stores.
// __syncthreads drains vmcnt, so phase-A stores are L2-visible before the
// phase-E zero overwrites.
__global__ __launch_bounds__(256) void fused_kernel(const float* __restrict__ unif,
                                                    const vf4* __restrict__ pr4,
                                                    const vf4* __restrict__ wd4,
                                                    float* __restrict__ out) {
  __shared__ uint64_t sPos[NCHP];    // contiguous positivity bits (later: z)
  __shared__ uint64_t sKeep[NCHP];   // phase A: ballot staging; D: keep bits
  __shared__ uint64_t sLv[4];        // live = R & O
  __shared__ int sQn;
  __shared__ unsigned short sQ[NCH];

  const int tid  = threadIdx.x;
  const int lane = tid & 63;
  const int wv   = tid >> 6;
  const int row  = blockIdx.x;
  const vf4* up4 = (const vf4*)(unif + (size_t)row * PTOT);
  vf4*       op4 = (vf4*)(out + (size_t)row * PTOT);
  float*     op  = out + (size_t)row * PTOT;

  if (tid == 0) sQn = 0;

  // ---- Phase A: stream + ballot (2-deep software pipeline) ---------------
  {
    int G = wv;
    vf4 u = {0.f,0.f,0.f,0.f}, p = {0.f,0.f,0.f,0.f}, w = {1.f,1.f,1.f,1.f};
    bool inb = false;
    if (G < NGRP) {
      int e4 = G * 64 + lane;
      inb = e4 < (PTOT / 4);
      u = inb ? __builtin_nontemporal_load(&up4[e4]) : (vf4){0.f,0.f,0.f,0.f};
      p = pr4[e4]; w = wd4[e4];
    }
    while (G < NGRP) {
      const int Gn = G + 4;
      vf4 un = {0.f,0.f,0.f,0.f}, pn = {0.f,0.f,0.f,0.f}, wn = {1.f,1.f,1.f,1.f};
      bool inbn = false;
      if (Gn < NGRP) {
        int e4n = Gn * 64 + lane;
        inbn = e4n < (PTOT / 4);
        un = inbn ? __builtin_nontemporal_load(&up4[e4n]) : (vf4){0.f,0.f,0.f,0.f};
        pn = pr4[e4n]; wn = wd4[e4n];
      }
      float m0 = __fadd_rn(__fdiv_rn(__fsub_rn(p.x, u.x), w.x), 0.5f);
      float m1 = __fadd_rn(__fdiv_rn(__fsub_rn(p.y, u.y), w.y), 0.5f);
      float m2 = __fadd_rn(__fdiv_rn(__fsub_rn(p.z, u.z), w.z), 0.5f);
      float m3 = __fadd_rn(__fdiv_rn(__fsub_rn(p.w, u.w), w.w), 0.5f);
      if (inb) {
        int e4 = G * 64 + lane;
        vf4 o;
        o.x = fminf(fmaxf(m0, 0.0f), 1.0f);
        o.y = fminf(fmaxf(m1, 0.0f), 1.0f);
        o.z = fminf(fmaxf(m2, 0.0f), 1.0f);
        o.w = fminf(fmaxf(m3, 0.0f), 1.0f);
        __builtin_nontemporal_store(o, &op4[e4]);
      }
      uint64_t b0 = __ballot(inb && (m0 > 0.0f));
      uint64_t b1 = __ballot(inb && (m1 > 0.0f));
      uint64_t b2 = __ballot(inb && (m2 > 0.0f));
      uint64_t b3 = __ballot(inb && (m3 > 0.0f));
      if (lane < 4) {
        uint64_t v = (lane == 0) ? b0 : (lane == 1) ? b1 : (lane == 2) ? b2 : b3;
        sKeep[G * 4 + lane] = v;
      }
      G = Gn; u = un; p = pn; w = wn; inb = inbn;
    }
  }
  __syncthreads();

  // ---- Phase B: deinterleave ballots -> contiguous-bit words; zero sKeep --
  for (int G = tid; G < NGRP; G += 256) {
    uint64_t b0 = sKeep[4 * G], b1 = sKeep[4 * G + 1];
    uint64_t b2 = sKeep[4 * G + 2], b3 = sKeep[4 * G + 3];
#pragma unroll
    for (int q = 0; q < 4; ++q) {
      uint64_t v = spread4((b0 >> (16 * q)) & 0xFFFFull)
                 | (spread4((b1 >> (16 * q)) & 0xFFFFull) << 1)
                 | (spread4((b2 >> (16 * q)) & 0xFFFFull) << 2)
                 | (spread4((b3 >> (16 * q)) & 0xFFFFull) << 3);
      sPos[4 * G + q] = v;
      sKeep[4 * G + q] = 0ull;
    }
  }
  for (int w = BMW + tid; w < NCHP; w += 256) { sPos[w] = 0ull; sKeep[w] = 0ull; }
  __syncthreads();

  // ---- Phase C: forward R then backward O on wave 0 -----------------------
  if (tid < 64) {
    uint64_t R0 = 3ull, R1 = 0ull, R2 = 0ull;
    const int g = lane;
#pragma unroll
    for (int L = 0; L < NL; ++L) {
      const int Vq = 2 + 13 * L;
      const int b  = c_base[L];
      bool pred = false;
      if (g < 36) {
        uint32_t off = (uint32_t)(b + g * Vq);
        uint64_t e0 = ext(sPos, off), e1 = ext(sPos, off + 64), e2 = ext(sPos, off + 128);
        pred = ((e0 & R0) | (e1 & R1) | (e2 & R2)) != 0ull;
      }
      uint64_t bal = __ballot(pred);
      uint64_t ar  = bal & (bal >> 12) & (bal >> 24) & 0xFFFull;
      orAt(R0, R1, R2, ar, (uint32_t)Vq);
      const int Vm = Vq + 12;
      uint32_t offm = (uint32_t)(b + 36 * Vq);
      uint64_t e0 = ext(sPos, offm), e1 = ext(sPos, offm + 64), e2 = ext(sPos, offm + 128);
      uint64_t mr = (((e0 & R0) | (e1 & R1) | (e2 & R2)) != 0ull) ? 1ull : 0ull;
      orAt(R0, R1, R2, mr, (uint32_t)Vm);
    }

    // backward liveness with on-the-fly R-masking (O ⊆ R)
    uint64_t O0 = ext(sPos, LMB)       & R0;
    uint64_t O1 = ext(sPos, LMB + 64)  & R1;
    uint64_t O2 = ext(sPos, LMB + 128) & ((1ull << 30) - 1ull) & R2;
    const int hg = g % 12;
#pragma unroll
    for (int L = NL - 1; L >= 0; --L) {
      const int Vq = 2 + 13 * L, Vm = Vq + 12;
      const int b  = c_base[L];
      if (rbit(O0, O1, O2, (uint32_t)Vm)) {
        uint64_t m0, m1, m2; maskLen((uint32_t)Vm, m0, m1, m2);
        uint32_t offm = (uint32_t)(b + 36 * Vq);
        O0 |= ext(sPos, offm)       & R0 & m0;
        O1 |= ext(sPos, offm + 64)  & R1 & m1;
        O2 |= ext(sPos, offm + 128) & R2 & m2;
      }
      uint32_t h12 = ext12(O0, O1, O2, (uint32_t)Vq);
      uint64_t q0, q1, q2; maskLen((uint32_t)Vq, q0, q1, q2);
      uint64_t c0 = 0ull, c1 = 0ull, c2 = 0ull;
      if (g < 36 && ((h12 >> hg) & 1u)) {
        uint32_t off = (uint32_t)(b + g * Vq);
        c0 = ext(sPos, off)       & R0 & q0;
        c1 = ext(sPos, off + 64)  & R1 & q1;
        c2 = ext(sPos, off + 128) & R2 & q2;
      }
#pragma unroll
      for (int d = 32; d; d >>= 1) {
        c0 |= __shfl_xor((unsigned long long)c0, d);
        c1 |= __shfl_xor((unsigned long long)c1, d);
        c2 |= __shfl_xor((unsigned long long)c2, d);
      }
      O0 |= c0; O1 |= c1; O2 |= c2;
    }
    if (lane == 0) {
      sLv[0] = R0 & O0; sLv[1] = R1 & O1; sLv[2] = R2 & O2; sLv[3] = 0ull;
    }
  }
  __syncthreads();

  // ---- Phase D: build keep bitvector via shifted live windows -------------
  {
    const uint64_t l0 = sLv[0], l1 = sLv[1], l2 = sLv[2];
    for (int s = tid; s < NSEG; s += 256) {
      uint32_t p0, len;
      bool olive;
      if (s == NSEG - 1) {               // LM tail: keep[i] = live[i]
        p0 = LMB; len = 158; olive = true;
      } else {
        int L = s / 37, j = s - L * 37;
        int Vq = 2 + 13 * L, b = c_base[L];
        if (j < 36) { p0 = (uint32_t)(b + j * Vq); len = (uint32_t)Vq;
                      olive = rbit(l0, l1, l2, (uint32_t)(Vq + (j % 12))) != 0ull; }
        else        { p0 = (uint32_t)(b + 36 * Vq); len = (uint32_t)(Vq + 12);
                      olive = rbit(l0, l1, l2, (uint32_t)(Vq + 12)) != 0ull; }
      }
      if (!olive) continue;
      uint32_t w0 = p0 >> 6, s0 = p0 & 63;
      uint64_t first = l0;
      if (len < 64) first &= (1ull << len) - 1ull;
      atomicOr((unsigned long long*)&sKeep[w0], (unsigned long long)(first << s0));
      uint32_t done = 64 - s0;
      uint32_t w = w0 + 1;
      while (done < len) {
        uint64_t v = rext(l0, l1, l2, done);
        uint32_t rem = len - done;
        if (rem < 64) v &= (1ull << rem) - 1ull;
        atomicOr((unsigned long long*)&sKeep[w], (unsigned long long)v);
        done += 64; ++w;
      }
    }
  }
  __syncthreads();

  // ---- Phase E: z-words + queue, then coalesced zero stores ---------------
  for (int w = tid; w < NCH; w += 256) {
    uint64_t pm = sPos[w];
    if (!pm) continue;
    uint64_t z = pm & ~sKeep[w];        // was >0 but pruned -> must write 0
    if (z) {
      sPos[w] = z;
      int k = atomicAdd(&sQn, 1);
      sQ[k] = (unsigned short)w;
    }
  }
  __syncthreads();
  {
    const int qn = sQn;
    for (int k = wv; k < qn; k += 4) {
      int w = sQ[k];
      uint64_t z = sPos[w];
      if ((z >> lane) & 1ull) op[w * 64 + lane] = 0.0f;
    }
  }
}

extern "C" void kernel_launch(void* const* d_in, const int* in_sizes, int n_in,
                              void* d_out, int out_size, void* d_ws, size_t ws_size,
                              hipStream_t stream) {
  const float* sp   = (const float*)d_in[0];
  const float* unif = (const float*)d_in[1];
  float* out = (float*)d_out;
  char* ws = (char*)d_ws;
  float* pr = (float*)ws;                                  // 132096 B
  float* wd = (float*)(ws + 132096);                       // 132096 B
  int bz = in_sizes[1] / PTOT;   // 1024

  init_tables<<<dim3(TPAD / 256), dim3(256), 0, stream>>>(sp, pr, wd);
  fused_kernel<<<dim3(bz), dim3(256), 0, stream>>>(
      unif, (const vf4*)pr, (const vf4*)wd, out);
}

// Round 4
// 304.059 us; speedup vs baseline: 1.1103x; 1.0116x over previous
//
#include <hip/hip_runtime.h>
#include <stdint.h>

#define NL   12
#define PTOT 32936
#define LMB  32778
#define NCH  515           // ceil(PTOT/64) words of positivity bits
#define NCHP 520           // padded LDS words
#define NGRP 129           // ceil(NCH/4) 256-elem groups (64 float4 / group)
#define BMW  (NGRP * 4)    // 516 ballot words (interleaved layout)
#define TPAD (NGRP * 256)  // 33024 padded table elems
#define NSEG 445           // 12 layers * 37 segments + 1 LM segment
#define TPB  512           // threads per block (8 waves -> full CU occupancy)
#define NWV  (TPB / 64)

typedef float vf4 __attribute__((ext_vector_type(4)));

__device__ __constant__ int c_base[NL] = {0,86,653,1701,3230,5240,7731,10703,14156,18090,22505,27401};

__device__ __forceinline__ uint64_t ext(const uint64_t* P, uint32_t off) {
  uint32_t w = off >> 6, s = off & 63;
  uint64_t lo = P[w], hi = P[w + 1];
  return s ? ((lo >> s) | (hi << (64 - s))) : lo;
}

__device__ __forceinline__ uint64_t rbit(uint64_t r0, uint64_t r1, uint64_t r2, uint32_t idx) {
  uint64_t w = idx < 64 ? r0 : (idx < 128 ? r1 : r2);
  return (w >> (idx & 63)) & 1ull;
}

// register-resident ext over the 158-bit live vector (bits >=192 implied 0)
__device__ __forceinline__ uint64_t rext(uint64_t a0, uint64_t a1, uint64_t a2, uint32_t off) {
  uint32_t w = off >> 6, s = off & 63;
  uint64_t lo = (w == 0) ? a0 : ((w == 1) ? a1 : ((w == 2) ? a2 : 0ull));
  uint64_t hi = (w == 0) ? a1 : ((w == 1) ? a2 : 0ull);
  return s ? ((lo >> s) | (hi << (64 - s))) : lo;
}

__device__ __forceinline__ void orAt(uint64_t& r0, uint64_t& r1, uint64_t& r2,
                                     uint64_t val, uint32_t pos) {
  uint32_t w = pos >> 6, s = pos & 63;
  uint64_t lo = val << s;
  uint64_t hi = s ? (val >> (64 - s)) : 0ull;
  if (w == 0) { r0 |= lo; r1 |= hi; }
  else if (w == 1) { r1 |= lo; r2 |= hi; }
  else { r2 |= lo; }
}

__device__ __forceinline__ void maskLen(uint32_t len, uint64_t& m0, uint64_t& m1, uint64_t& m2) {
  m0 = (len >= 64) ? ~0ull : ((1ull << len) - 1ull);
  m1 = (len <= 64) ? 0ull : ((len >= 128) ? ~0ull : ((1ull << (len - 64)) - 1ull));
  m2 = (len <= 128) ? 0ull : ((1ull << (len - 128)) - 1ull);
}

__device__ __forceinline__ uint32_t ext12(uint64_t O0, uint64_t O1, uint64_t O2, uint32_t pos) {
  uint32_t w = pos >> 6, s = pos & 63;
  uint64_t lo = (w == 0) ? O0 : ((w == 1) ? O1 : O2);
  uint64_t hi = (w == 0) ? O1 : ((w == 1) ? O2 : 0ull);
  uint64_t v = s ? ((lo >> s) | (hi << (64 - s))) : lo;
  return (uint32_t)v & 0xFFFu;
}

// spread 16 bits to every 4th bit of a 64-bit word
__device__ __forceinline__ uint64_t spread4(uint64_t x) {
  x = (x | (x << 24)) & 0x000000FF000000FFull;
  x = (x | (x << 12)) & 0x000F000F000F000Full;
  x = (x | (x << 6))  & 0x0303030303030303ull;
  x = (x | (x << 3))  & 0x1111111111111111ull;
  return x;
}

// Per-param (prob', window) SoA tables.
__global__ void init_tables(const float* __restrict__ sp, float* __restrict__ pr,
                            float* __restrict__ wd) {
  int p = blockIdx.x * blockDim.x + threadIdx.x;
  if (p >= TPAD) return;
  if (p < PTOT) {
    float x = sp[p];
    float s = 1.0f / (1.0f + expf(-x));                 // sigmoid, fp32
    float w = __fmul_rn(s, __fsub_rn(1.0f, s));         // window = p*(1-p)
    float pv = __fadd_rn(__fmul_rn(w, s), __fmul_rn(__fsub_rn(1.0f, w), s));
    pr[p] = pv; wd[p] = w;
  } else {
    pr[p] = 0.0f; wd[p] = 1.0f;
  }
}

// ---- Fused kernel: one 512-thread block per row -----------------------------
// 8 waves/block, 4 blocks/CU resident -> 2048 threads/CU (full occupancy);
// 8 waves/SIMD gives enough co-resident compute to hide the ~600-900cy
// u-load latency that capped the 256-thread version at 29% HBM BW.
// Phase A : stream unif -> masks -> out (nontemporal), ballot positivity
//           bits straight into LDS.
// Phase B : deinterleave ballots into contiguous-bit words (spread4).
// Phase C : wave 0: forward reachability R then backward liveness O with
//           on-the-fly R-masking (O ⊆ R); live = R & O.
// Phase D : per-segment shifted-window keep build.
// Phase E : z-words + queue, coalesced lane-predicated zero stores.
__global__ __launch_bounds__(TPB) void fused_kernel(const float* __restrict__ unif,
                                                    const vf4* __restrict__ pr4,
                                                    const vf4* __restrict__ wd4,
                                                    float* __restrict__ out) {
  __shared__ uint64_t sPos[NCHP];    // contiguous positivity bits (later: z)
  __shared__ uint64_t sKeep[NCHP];   // phase A: ballot staging; D: keep bits
  __shared__ uint64_t sLv[4];        // live = R & O
  __shared__ int sQn;
  __shared__ unsigned short sQ[NCH];

  const int tid  = threadIdx.x;
  const int lane = tid & 63;
  const int wv   = tid >> 6;
  const int row  = blockIdx.x;
  const vf4* up4 = (const vf4*)(unif + (size_t)row * PTOT);
  vf4*       op4 = (vf4*)(out + (size_t)row * PTOT);
  float*     op  = out + (size_t)row * PTOT;

  if (tid == 0) sQn = 0;

  // ---- Phase A: stream + ballot (2-deep software pipeline) ---------------
  {
    int G = wv;
    vf4 u = {0.f,0.f,0.f,0.f}, p = {0.f,0.f,0.f,0.f}, w = {1.f,1.f,1.f,1.f};
    bool inb = false;
    if (G < NGRP) {
      int e4 = G * 64 + lane;
      inb = e4 < (PTOT / 4);
      u = inb ? __builtin_nontemporal_load(&up4[e4]) : (vf4){0.f,0.f,0.f,0.f};
      p = pr4[e4]; w = wd4[e4];
    }
    while (G < NGRP) {
      const int Gn = G + NWV;
      vf4 un = {0.f,0.f,0.f,0.f}, pn = {0.f,0.f,0.f,0.f}, wn = {1.f,1.f,1.f,1.f};
      bool inbn = false;
      if (Gn < NGRP) {
        int e4n = Gn * 64 + lane;
        inbn = e4n < (PTOT / 4);
        un = inbn ? __builtin_nontemporal_load(&up4[e4n]) : (vf4){0.f,0.f,0.f,0.f};
        pn = pr4[e4n]; wn = wd4[e4n];
      }
      float m0 = __fadd_rn(__fdiv_rn(__fsub_rn(p.x, u.x), w.x), 0.5f);
      float m1 = __fadd_rn(__fdiv_rn(__fsub_rn(p.y, u.y), w.y), 0.5f);
      float m2 = __fadd_rn(__fdiv_rn(__fsub_rn(p.z, u.z), w.z), 0.5f);
      float m3 = __fadd_rn(__fdiv_rn(__fsub_rn(p.w, u.w), w.w), 0.5f);
      if (inb) {
        int e4 = G * 64 + lane;
        vf4 o;
        o.x = fminf(fmaxf(m0, 0.0f), 1.0f);
        o.y = fminf(fmaxf(m1, 0.0f), 1.0f);
        o.z = fminf(fmaxf(m2, 0.0f), 1.0f);
        o.w = fminf(fmaxf(m3, 0.0f), 1.0f);
        __builtin_nontemporal_store(o, &op4[e4]);
      }
      uint64_t b0 = __ballot(inb && (m0 > 0.0f));
      uint64_t b1 = __ballot(inb && (m1 > 0.0f));
      uint64_t b2 = __ballot(inb && (m2 > 0.0f));
      uint64_t b3 = __ballot(inb && (m3 > 0.0f));
      if (lane < 4) {
        uint64_t v = (lane == 0) ? b0 : (lane == 1) ? b1 : (lane == 2) ? b2 : b3;
        sKeep[G * 4 + lane] = v;
      }
      G = Gn; u = un; p = pn; w = wn; inb = inbn;
    }
  }
  __syncthreads();

  // ---- Phase B: deinterleave ballots -> contiguous-bit words; zero sKeep --
  for (int G = tid; G < NGRP; G += TPB) {
    uint64_t b0 = sKeep[4 * G], b1 = sKeep[4 * G + 1];
    uint64_t b2 = sKeep[4 * G + 2], b3 = sKeep[4 * G + 3];
#pragma unroll
    for (int q = 0; q < 4; ++q) {
      uint64_t v = spread4((b0 >> (16 * q)) & 0xFFFFull)
                 | (spread4((b1 >> (16 * q)) & 0xFFFFull) << 1)
                 | (spread4((b2 >> (16 * q)) & 0xFFFFull) << 2)
                 | (spread4((b3 >> (16 * q)) & 0xFFFFull) << 3);
      sPos[4 * G + q] = v;
      sKeep[4 * G + q] = 0ull;
    }
  }
  for (int w = BMW + tid; w < NCHP; w += TPB) { sPos[w] = 0ull; sKeep[w] = 0ull; }
  __syncthreads();

  // ---- Phase C: forward R then backward O on wave 0 -----------------------
  if (tid < 64) {
    uint64_t R0 = 3ull, R1 = 0ull, R2 = 0ull;
    const int g = lane;
#pragma unroll
    for (int L = 0; L < NL; ++L) {
      const int Vq = 2 + 13 * L;
      const int b  = c_base[L];
      bool pred = false;
      if (g < 36) {
        uint32_t off = (uint32_t)(b + g * Vq);
        uint64_t e0 = ext(sPos, off), e1 = ext(sPos, off + 64), e2 = ext(sPos, off + 128);
        pred = ((e0 & R0) | (e1 & R1) | (e2 & R2)) != 0ull;
      }
      uint64_t bal = __ballot(pred);
      uint64_t ar  = bal & (bal >> 12) & (bal >> 24) & 0xFFFull;
      orAt(R0, R1, R2, ar, (uint32_t)Vq);
      const int Vm = Vq + 12;
      uint32_t offm = (uint32_t)(b + 36 * Vq);
      uint64_t e0 = ext(sPos, offm), e1 = ext(sPos, offm + 64), e2 = ext(sPos, offm + 128);
      uint64_t mr = (((e0 & R0) | (e1 & R1) | (e2 & R2)) != 0ull) ? 1ull : 0ull;
      orAt(R0, R1, R2, mr, (uint32_t)Vm);
    }

    // backward liveness with on-the-fly R-masking (O ⊆ R)
    uint64_t O0 = ext(sPos, LMB)       & R0;
    uint64_t O1 = ext(sPos, LMB + 64)  & R1;
    uint64_t O2 = ext(sPos, LMB + 128) & ((1ull << 30) - 1ull) & R2;
    const int hg = g % 12;
#pragma unroll
    for (int L = NL - 1; L >= 0; --L) {
      const int Vq = 2 + 13 * L, Vm = Vq + 12;
      const int b  = c_base[L];
      if (rbit(O0, O1, O2, (uint32_t)Vm)) {
        uint64_t m0, m1, m2; maskLen((uint32_t)Vm, m0, m1, m2);
        uint32_t offm = (uint32_t)(b + 36 * Vq);
        O0 |= ext(sPos, offm)       & R0 & m0;
        O1 |= ext(sPos, offm + 64)  & R1 & m1;
        O2 |= ext(sPos, offm + 128) & R2 & m2;
      }
      uint32_t h12 = ext12(O0, O1, O2, (uint32_t)Vq);
      uint64_t q0, q1, q2; maskLen((uint32_t)Vq, q0, q1, q2);
      uint64_t c0 = 0ull, c1 = 0ull, c2 = 0ull;
      if (g < 36 && ((h12 >> hg) & 1u)) {
        uint32_t off = (uint32_t)(b + g * Vq);
        c0 = ext(sPos, off)       & R0 & q0;
        c1 = ext(sPos, off + 64)  & R1 & q1;
        c2 = ext(sPos, off + 128) & R2 & q2;
      }
#pragma unroll
      for (int d = 32; d; d >>= 1) {
        c0 |= __shfl_xor((unsigned long long)c0, d);
        c1 |= __shfl_xor((unsigned long long)c1, d);
        c2 |= __shfl_xor((unsigned long long)c2, d);
      }
      O0 |= c0; O1 |= c1; O2 |= c2;
    }
    if (lane == 0) {
      sLv[0] = R0 & O0; sLv[1] = R1 & O1; sLv[2] = R2 & O2; sLv[3] = 0ull;
    }
  }
  __syncthreads();

  // ---- Phase D: build keep bitvector via shifted live windows -------------
  {
    const uint64_t l0 = sLv[0], l1 = sLv[1], l2 = sLv[2];
    for (int s = tid; s < NSEG; s += TPB) {
      uint32_t p0, len;
      bool olive;
      if (s == NSEG - 1) {               // LM tail: keep[i] = live[i]
        p0 = LMB; len = 158; olive = true;
      } else {
        int L = s / 37, j = s - L * 37;
        int Vq = 2 + 13 * L, b = c_base[L];
        if (j < 36) { p0 = (uint32_t)(b + j * Vq); len = (uint32_t)Vq;
                      olive = rbit(l0, l1, l2, (uint32_t)(Vq + (j % 12))) != 0ull; }
        else        { p0 = (uint32_t)(b + 36 * Vq); len = (uint32_t)(Vq + 12);
                      olive = rbit(l0, l1, l2, (uint32_t)(Vq + 12)) != 0ull; }
      }
      if (!olive) continue;
      uint32_t w0 = p0 >> 6, s0 = p0 & 63;
      uint64_t first = l0;
      if (len < 64) first &= (1ull << len) - 1ull;
      atomicOr((unsigned long long*)&sKeep[w0], (unsigned long long)(first << s0));
      uint32_t done = 64 - s0;
      uint32_t w = w0 + 1;
      while (done < len) {
        uint64_t v = rext(l0, l1, l2, done);
        uint32_t rem = len - done;
        if (rem < 64) v &= (1ull << rem) - 1ull;
        atomicOr((unsigned long long*)&sKeep[w], (unsigned long long)v);
        done += 64; ++w;
      }
    }
  }
  __syncthreads();

  // ---- Phase E: z-words + queue, then coalesced zero stores ---------------
  for (int w = tid; w < NCH; w += TPB) {
    uint64_t pm = sPos[w];
    if (!pm) continue;
    uint64_t z = pm & ~sKeep[w];        // was >0 but pruned -> must write 0
    if (z) {
      sPos[w] = z;
      int k = atomicAdd(&sQn, 1);
      sQ[k] = (unsigned short)w;
    }
  }
  __syncthreads();
  {
    const int qn = sQn;
    for (int k = wv; k < qn; k += NWV) {
      int w = sQ[k];
      uint64_t z = sPos[w];
      if ((z >> lane) & 1ull) op[w * 64 + lane] = 0.0f;
    }
  }
}

extern "C" void kernel_launch(void* const* d_in, const int* in_sizes, int n_in,
                              void* d_out, int out_size, void* d_ws, size_t ws_size,
                              hipStream_t stream) {
  const float* sp   = (const float*)d_in[0];
  const float* unif = (const float*)d_in[1];
  float* out = (float*)d_out;
  char* ws = (char*)d_ws;
  float* pr = (float*)ws;                                  // 132096 B
  float* wd = (float*)(ws + 132096);                       // 132096 B
  int bz = in_sizes[1] / PTOT;   // 1024

  init_tables<<<dim3(TPAD / 256), dim3(256), 0, stream>>>(sp, pr, wd);
  fused_kernel<<<dim3(bz), dim3(TPB), 0, stream>>>(
      unif, (const vf4*)pr, (const vf4*)wd, out);
}

// Round 8
// 269.564 us; speedup vs baseline: 1.2524x; 1.1280x over previous
//
#include <hip/hip_runtime.h>
#include <stdint.h>

#define NL   12
#define PTOT 32936
#define LMB  32778
#define NCH  515           // ceil(PTOT/64) words of positivity bits
#define NCHP 520           // padded LDS words
#define NGRP 129           // ceil(NCH/4) 256-elem groups (64 float4 / group)
#define BMW  (NGRP * 4)    // 516 ballot words (interleaved layout)
#define TPAD (NGRP * 256)  // 33024 padded table elems
#define NSEG 445           // 12 layers * 37 segments + 1 LM segment
#define TPB  512           // threads per block (8 waves)
#define NWV  (TPB / 64)

typedef float vf4 __attribute__((ext_vector_type(4)));

__device__ __constant__ int c_base[NL] = {0,86,653,1701,3230,5240,7731,10703,14156,18090,22505,27401};

__device__ __forceinline__ uint64_t ext(const uint64_t* P, uint32_t off) {
  uint32_t w = off >> 6, s = off & 63;
  uint64_t lo = P[w], hi = P[w + 1];
  return s ? ((lo >> s) | (hi << (64 - s))) : lo;
}

__device__ __forceinline__ uint64_t rbit(uint64_t r0, uint64_t r1, uint64_t r2, uint32_t idx) {
  uint64_t w = idx < 64 ? r0 : (idx < 128 ? r1 : r2);
  return (w >> (idx & 63)) & 1ull;
}

// register-resident ext over the 158-bit live vector (bits >=192 implied 0)
__device__ __forceinline__ uint64_t rext(uint64_t a0, uint64_t a1, uint64_t a2, uint32_t off) {
  uint32_t w = off >> 6, s = off & 63;
  uint64_t lo = (w == 0) ? a0 : ((w == 1) ? a1 : ((w == 2) ? a2 : 0ull));
  uint64_t hi = (w == 0) ? a1 : ((w == 1) ? a2 : 0ull);
  return s ? ((lo >> s) | (hi << (64 - s))) : lo;
}

__device__ __forceinline__ void orAt(uint64_t& r0, uint64_t& r1, uint64_t& r2,
                                     uint64_t val, uint32_t pos) {
  uint32_t w = pos >> 6, s = pos & 63;
  uint64_t lo = val << s;
  uint64_t hi = s ? (val >> (64 - s)) : 0ull;
  if (w == 0) { r0 |= lo; r1 |= hi; }
  else if (w == 1) { r1 |= lo; r2 |= hi; }
  else { r2 |= lo; }
}

__device__ __forceinline__ void maskLen(uint32_t len, uint64_t& m0, uint64_t& m1, uint64_t& m2) {
  m0 = (len >= 64) ? ~0ull : ((1ull << len) - 1ull);
  m1 = (len <= 64) ? 0ull : ((len >= 128) ? ~0ull : ((1ull << (len - 64)) - 1ull));
  m2 = (len <= 128) ? 0ull : ((1ull << (len - 128)) - 1ull);
}

__device__ __forceinline__ uint32_t ext12(uint64_t O0, uint64_t O1, uint64_t O2, uint32_t pos) {
  uint32_t w = pos >> 6, s = pos & 63;
  uint64_t lo = (w == 0) ? O0 : ((w == 1) ? O1 : O2);
  uint64_t hi = (w == 0) ? O1 : ((w == 1) ? O2 : 0ull);
  uint64_t v = s ? ((lo >> s) | (hi << (64 - s))) : lo;
  return (uint32_t)v & 0xFFFu;
}

// spread 16 bits to every 4th bit of a 64-bit word
__device__ __forceinline__ uint64_t spread4(uint64_t x) {
  x = (x | (x << 24)) & 0x000000FF000000FFull;
  x = (x | (x << 12)) & 0x000F000F000F000Full;
  x = (x | (x << 6))  & 0x0303030303030303ull;
  x = (x | (x << 3))  & 0x1111111111111111ull;
  return x;
}

// Per-param (prob', window) SoA tables.
__global__ void init_tables(const float* __restrict__ sp, float* __restrict__ pr,
                            float* __restrict__ wd) {
  int p = blockIdx.x * blockDim.x + threadIdx.x;
  if (p >= TPAD) return;
  if (p < PTOT) {
    float x = sp[p];
    float s = 1.0f / (1.0f + expf(-x));                 // sigmoid, fp32
    float w = __fmul_rn(s, __fsub_rn(1.0f, s));         // window = p*(1-p)
    float pv = __fadd_rn(__fmul_rn(w, s), __fmul_rn(__fsub_rn(1.0f, w), s));
    pr[p] = pv; wd[p] = w;
  } else {
    pr[p] = 0.0f; wd[p] = 1.0f;
  }
}

// ---- Fused kernel: one 512-thread block per row -----------------------------
// No read-modify-write: out is written exactly once, in phase F.
//   out = keepbit ? clip(m) : 0   (when !pos, clip(m)==0, so pos factor free)
// Phase A : READ-ONLY stream: u -> m -> positivity ballots into LDS.
// Phase B : deinterleave ballots into contiguous-bit words (spread4).
// Phase C : wave 0: forward reachability R, backward liveness O (O ⊆ R),
//           live = R & O.
// Phase D : per-segment shifted-window keep build (edge map is piecewise
//           sequential: keep[seg] = out_live ? live[0..len) : 0).
// Phase F : re-read u (L2/L3-hot), recompute m identically, apply keep,
//           nontemporal full-line streaming store.
__global__ __launch_bounds__(TPB) void fused_kernel(const float* __restrict__ unif,
                                                    const vf4* __restrict__ pr4,
                                                    const vf4* __restrict__ wd4,
                                                    float* __restrict__ out) {
  __shared__ uint64_t sPos[NCHP];    // contiguous positivity bits
  __shared__ uint64_t sKeep[NCHP];   // phase A: ballot staging; D/F: keep bits
  __shared__ uint64_t sLv[4];        // live = R & O

  const int tid  = threadIdx.x;
  const int lane = tid & 63;
  const int wv   = tid >> 6;
  const int row  = blockIdx.x;
  const vf4* up4 = (const vf4*)(unif + (size_t)row * PTOT);
  vf4*       op4 = (vf4*)(out + (size_t)row * PTOT);

  // ---- Phase A: read-only stream + ballot (2-deep software pipeline) ------
  {
    int G = wv;
    vf4 u = {0.f,0.f,0.f,0.f}, p = {0.f,0.f,0.f,0.f}, w = {1.f,1.f,1.f,1.f};
    bool inb = false;
    if (G < NGRP) {
      int e4 = G * 64 + lane;
      inb = e4 < (PTOT / 4);
      u = inb ? up4[e4] : (vf4){0.f,0.f,0.f,0.f};   // normal load: allocate L3
      p = pr4[e4]; w = wd4[e4];
    }
    while (G < NGRP) {
      const int Gn = G + NWV;
      vf4 un = {0.f,0.f,0.f,0.f}, pn = {0.f,0.f,0.f,0.f}, wn = {1.f,1.f,1.f,1.f};
      bool inbn = false;
      if (Gn < NGRP) {
        int e4n = Gn * 64 + lane;
        inbn = e4n < (PTOT / 4);
        un = inbn ? up4[e4n] : (vf4){0.f,0.f,0.f,0.f};
        pn = pr4[e4n]; wn = wd4[e4n];
      }
      float m0 = __fadd_rn(__fdiv_rn(__fsub_rn(p.x, u.x), w.x), 0.5f);
      float m1 = __fadd_rn(__fdiv_rn(__fsub_rn(p.y, u.y), w.y), 0.5f);
      float m2 = __fadd_rn(__fdiv_rn(__fsub_rn(p.z, u.z), w.z), 0.5f);
      float m3 = __fadd_rn(__fdiv_rn(__fsub_rn(p.w, u.w), w.w), 0.5f);
      uint64_t b0 = __ballot(inb && (m0 > 0.0f));
      uint64_t b1 = __ballot(inb && (m1 > 0.0f));
      uint64_t b2 = __ballot(inb && (m2 > 0.0f));
      uint64_t b3 = __ballot(inb && (m3 > 0.0f));
      if (lane < 4) {
        uint64_t v = (lane == 0) ? b0 : (lane == 1) ? b1 : (lane == 2) ? b2 : b3;
        sKeep[G * 4 + lane] = v;
      }
      G = Gn; u = un; p = pn; w = wn; inb = inbn;
    }
  }
  __syncthreads();

  // ---- Phase B: deinterleave ballots -> contiguous-bit words; zero sKeep --
  for (int G = tid; G < NGRP; G += TPB) {
    uint64_t b0 = sKeep[4 * G], b1 = sKeep[4 * G + 1];
    uint64_t b2 = sKeep[4 * G + 2], b3 = sKeep[4 * G + 3];
#pragma unroll
    for (int q = 0; q < 4; ++q) {
      uint64_t v = spread4((b0 >> (16 * q)) & 0xFFFFull)
                 | (spread4((b1 >> (16 * q)) & 0xFFFFull) << 1)
                 | (spread4((b2 >> (16 * q)) & 0xFFFFull) << 2)
                 | (spread4((b3 >> (16 * q)) & 0xFFFFull) << 3);
      sPos[4 * G + q] = v;
      sKeep[4 * G + q] = 0ull;
    }
  }
  for (int w = BMW + tid; w < NCHP; w += TPB) { sPos[w] = 0ull; sKeep[w] = 0ull; }
  __syncthreads();

  // ---- Phase C: forward R then backward O on wave 0 -----------------------
  if (tid < 64) {
    uint64_t R0 = 3ull, R1 = 0ull, R2 = 0ull;
    const int g = lane;
#pragma unroll
    for (int L = 0; L < NL; ++L) {
      const int Vq = 2 + 13 * L;
      const int b  = c_base[L];
      bool pred = false;
      if (g < 36) {
        uint32_t off = (uint32_t)(b + g * Vq);
        uint64_t e0 = ext(sPos, off), e1 = ext(sPos, off + 64), e2 = ext(sPos, off + 128);
        pred = ((e0 & R0) | (e1 & R1) | (e2 & R2)) != 0ull;
      }
      uint64_t bal = __ballot(pred);
      uint64_t ar  = bal & (bal >> 12) & (bal >> 24) & 0xFFFull;
      orAt(R0, R1, R2, ar, (uint32_t)Vq);
      const int Vm = Vq + 12;
      uint32_t offm = (uint32_t)(b + 36 * Vq);
      uint64_t e0 = ext(sPos, offm), e1 = ext(sPos, offm + 64), e2 = ext(sPos, offm + 128);
      uint64_t mr = (((e0 & R0) | (e1 & R1) | (e2 & R2)) != 0ull) ? 1ull : 0ull;
      orAt(R0, R1, R2, mr, (uint32_t)Vm);
    }

    // backward liveness with on-the-fly R-masking (O ⊆ R)
    uint64_t O0 = ext(sPos, LMB)       & R0;
    uint64_t O1 = ext(sPos, LMB + 64)  & R1;
    uint64_t O2 = ext(sPos, LMB + 128) & ((1ull << 30) - 1ull) & R2;
    const int hg = g % 12;
#pragma unroll
    for (int L = NL - 1; L >= 0; --L) {
      const int Vq = 2 + 13 * L, Vm = Vq + 12;
      const int b  = c_base[L];
      if (rbit(O0, O1, O2, (uint32_t)Vm)) {
        uint64_t m0, m1, m2; maskLen((uint32_t)Vm, m0, m1, m2);
        uint32_t offm = (uint32_t)(b + 36 * Vq);
        O0 |= ext(sPos, offm)       & R0 & m0;
        O1 |= ext(sPos, offm + 64)  & R1 & m1;
        O2 |= ext(sPos, offm + 128) & R2 & m2;
      }
      uint32_t h12 = ext12(O0, O1, O2, (uint32_t)Vq);
      uint64_t q0, q1, q2; maskLen((uint32_t)Vq, q0, q1, q2);
      uint64_t c0 = 0ull, c1 = 0ull, c2 = 0ull;
      if (g < 36 && ((h12 >> hg) & 1u)) {
        uint32_t off = (uint32_t)(b + g * Vq);
        c0 = ext(sPos, off)       & R0 & q0;
        c1 = ext(sPos, off + 64)  & R1 & q1;
        c2 = ext(sPos, off + 128) & R2 & q2;
      }
#pragma unroll
      for (int d = 32; d; d >>= 1) {
        c0 |= __shfl_xor((unsigned long long)c0, d);
        c1 |= __shfl_xor((unsigned long long)c1, d);
        c2 |= __shfl_xor((unsigned long long)c2, d);
      }
      O0 |= c0; O1 |= c1; O2 |= c2;
    }
    if (lane == 0) {
      sLv[0] = R0 & O0; sLv[1] = R1 & O1; sLv[2] = R2 & O2; sLv[3] = 0ull;
    }
  }
  __syncthreads();

  // ---- Phase D: build keep bitvector via shifted live windows -------------
  {
    const uint64_t l0 = sLv[0], l1 = sLv[1], l2 = sLv[2];
    for (int s = tid; s < NSEG; s += TPB) {
      uint32_t p0, len;
      bool olive;
      if (s == NSEG - 1) {               // LM tail: keep[i] = live[i]
        p0 = LMB; len = 158; olive = true;
      } else {
        int L = s / 37, j = s - L * 37;
        int Vq = 2 + 13 * L, b = c_base[L];
        if (j < 36) { p0 = (uint32_t)(b + j * Vq); len = (uint32_t)Vq;
                      olive = rbit(l0, l1, l2, (uint32_t)(Vq + (j % 12))) != 0ull; }
        else        { p0 = (uint32_t)(b + 36 * Vq); len = (uint32_t)(Vq + 12);
                      olive = rbit(l0, l1, l2, (uint32_t)(Vq + 12)) != 0ull; }
      }
      if (!olive) continue;
      uint32_t w0 = p0 >> 6, s0 = p0 & 63;
      uint64_t first = l0;
      if (len < 64) first &= (1ull << len) - 1ull;
      atomicOr((unsigned long long*)&sKeep[w0], (unsigned long long)(first << s0));
      uint32_t done = 64 - s0;
      uint32_t w = w0 + 1;
      while (done < len) {
        uint64_t v = rext(l0, l1, l2, done);
        uint32_t rem = len - done;
        if (rem < 64) v &= (1ull << rem) - 1ull;
        atomicOr((unsigned long long*)&sKeep[w], (unsigned long long)v);
        done += 64; ++w;
      }
    }
  }
  __syncthreads();

  // ---- Phase F: recompute + keep-apply + single streaming store -----------
  // Param index of lane's element c: P = G*256 + 4*lane + c
  //   -> keep word G*4 + (lane>>4), bits 4*(lane&15)+c (nibble per lane).
  {
    const int sh = 4 * (lane & 15);
    const int kw0 = lane >> 4;
    for (int G = wv; G < NGRP; G += NWV) {
      int e4 = G * 64 + lane;
      bool inb = e4 < (PTOT / 4);
      vf4 u = inb ? up4[e4] : (vf4){0.f,0.f,0.f,0.f};   // L2/L3-hot re-read
      vf4 p = pr4[e4];
      vf4 w = wd4[e4];
      uint32_t k = (uint32_t)(sKeep[G * 4 + kw0] >> sh) & 0xFu;
      float m0 = __fadd_rn(__fdiv_rn(__fsub_rn(p.x, u.x), w.x), 0.5f);
      float m1 = __fadd_rn(__fdiv_rn(__fsub_rn(p.y, u.y), w.y), 0.5f);
      float m2 = __fadd_rn(__fdiv_rn(__fsub_rn(p.z, u.z), w.z), 0.5f);
      float m3 = __fadd_rn(__fdiv_rn(__fsub_rn(p.w, u.w), w.w), 0.5f);
      if (inb) {
        vf4 o;
        o.x = (k & 1u) ? fminf(fmaxf(m0, 0.0f), 1.0f) : 0.0f;
        o.y = (k & 2u) ? fminf(fmaxf(m1, 0.0f), 1.0f) : 0.0f;
        o.z = (k & 4u) ? fminf(fmaxf(m2, 0.0f), 1.0f) : 0.0f;
        o.w = (k & 8u) ? fminf(fmaxf(m3, 0.0f), 1.0f) : 0.0f;
        __builtin_nontemporal_store(o, &op4[e4]);
      }
    }
  }
}

extern "C" void kernel_launch(void* const* d_in, const int* in_sizes, int n_in,
                              void* d_out, int out_size, void* d_ws, size_t ws_size,
                              hipStream_t stream) {
  const float* sp   = (const float*)d_in[0];
  const float* unif = (const float*)d_in[1];
  float* out = (float*)d_out;
  char* ws = (char*)d_ws;
  float* pr = (float*)ws;                                  // 132096 B
  float* wd = (float*)(ws + 132096);                       // 132096 B
  int bz = in_sizes[1] / PTOT;   // 1024

  init_tables<<<dim3(TPAD / 256), dim3(256), 0, stream>>>(sp, pr, wd);
  fused_kernel<<<dim3(bz), dim3(TPB), 0, stream>>>(
      unif, (const vf4*)pr, (const vf4*)wd, out);
}

// Round 9
// 252.322 us; speedup vs baseline: 1.3380x; 1.0683x over previous
//
#include <hip/hip_runtime.h>
#include <stdint.h>

#define NL   12
#define PTOT 32936
#define LMB  32778
#define NCH  515           // ceil(PTOT/64) words of positivity bits
#define NCHP 520           // padded LDS words
#define NGRP 129           // ceil(NCH/4) 256-elem groups (64 float4 / group)
#define BMW  (NGRP * 4)    // 516 ballot words (interleaved layout)
#define TPAD (NGRP * 256)  // 33024 padded table elems
#define NSEG 445           // 12 layers * 37 segments + 1 LM segment
#define TPB  512           // threads per block (8 waves)
#define NWV  (TPB / 64)
#define NITER ((NGRP + NWV - 1) / NWV)   // 17 groups per wave (statically unrolled)

typedef float vf4 __attribute__((ext_vector_type(4)));

__device__ __constant__ int c_base[NL] = {0,86,653,1701,3230,5240,7731,10703,14156,18090,22505,27401};

__device__ __forceinline__ uint64_t ext(const uint64_t* P, uint32_t off) {
  uint32_t w = off >> 6, s = off & 63;
  uint64_t lo = P[w], hi = P[w + 1];
  return s ? ((lo >> s) | (hi << (64 - s))) : lo;
}

__device__ __forceinline__ uint64_t rbit(uint64_t r0, uint64_t r1, uint64_t r2, uint32_t idx) {
  uint64_t w = idx < 64 ? r0 : (idx < 128 ? r1 : r2);
  return (w >> (idx & 63)) & 1ull;
}

// register-resident ext over the 158-bit live vector (bits >=192 implied 0)
__device__ __forceinline__ uint64_t rext(uint64_t a0, uint64_t a1, uint64_t a2, uint32_t off) {
  uint32_t w = off >> 6, s = off & 63;
  uint64_t lo = (w == 0) ? a0 : ((w == 1) ? a1 : ((w == 2) ? a2 : 0ull));
  uint64_t hi = (w == 0) ? a1 : ((w == 1) ? a2 : 0ull);
  return s ? ((lo >> s) | (hi << (64 - s))) : lo;
}

__device__ __forceinline__ void orAt(uint64_t& r0, uint64_t& r1, uint64_t& r2,
                                     uint64_t val, uint32_t pos) {
  uint32_t w = pos >> 6, s = pos & 63;
  uint64_t lo = val << s;
  uint64_t hi = s ? (val >> (64 - s)) : 0ull;
  if (w == 0) { r0 |= lo; r1 |= hi; }
  else if (w == 1) { r1 |= lo; r2 |= hi; }
  else { r2 |= lo; }
}

__device__ __forceinline__ void maskLen(uint32_t len, uint64_t& m0, uint64_t& m1, uint64_t& m2) {
  m0 = (len >= 64) ? ~0ull : ((1ull << len) - 1ull);
  m1 = (len <= 64) ? 0ull : ((len >= 128) ? ~0ull : ((1ull << (len - 64)) - 1ull));
  m2 = (len <= 128) ? 0ull : ((1ull << (len - 128)) - 1ull);
}

__device__ __forceinline__ uint32_t ext12(uint64_t O0, uint64_t O1, uint64_t O2, uint32_t pos) {
  uint32_t w = pos >> 6, s = pos & 63;
  uint64_t lo = (w == 0) ? O0 : ((w == 1) ? O1 : O2);
  uint64_t hi = (w == 0) ? O1 : ((w == 1) ? O2 : 0ull);
  uint64_t v = s ? ((lo >> s) | (hi << (64 - s))) : lo;
  return (uint32_t)v & 0xFFFu;
}

// spread 16 bits to every 4th bit of a 64-bit word
__device__ __forceinline__ uint64_t spread4(uint64_t x) {
  x = (x | (x << 24)) & 0x000000FF000000FFull;
  x = (x | (x << 12)) & 0x000F000F000F000Full;
  x = (x | (x << 6))  & 0x0303030303030303ull;
  x = (x | (x << 3))  & 0x1111111111111111ull;
  return x;
}

// Per-param (prob', window) SoA tables.
__global__ void init_tables(const float* __restrict__ sp, float* __restrict__ pr,
                            float* __restrict__ wd) {
  int p = blockIdx.x * blockDim.x + threadIdx.x;
  if (p >= TPAD) return;
  if (p < PTOT) {
    float x = sp[p];
    float s = 1.0f / (1.0f + expf(-x));                 // sigmoid, fp32
    float w = __fmul_rn(s, __fsub_rn(1.0f, s));         // window = p*(1-p)
    float pv = __fadd_rn(__fmul_rn(w, s), __fmul_rn(__fsub_rn(1.0f, w), s));
    pr[p] = pv; wd[p] = w;
  } else {
    pr[p] = 0.0f; wd[p] = 1.0f;
  }
}

// ---- Fused kernel: one 512-thread block per row -----------------------------
// m values are computed ONCE in phase A and kept in a statically-indexed
// register array (17 x vf4 per thread); phase F applies the keep bits to the
// registered values and streams out. No re-read, no recompute, no RMW:
// HBM traffic = read unif once + write out once (compulsory minimum).
// __launch_bounds__(512,4): 4 waves/EU -> 16 waves/CU = 2 blocks/CU, VGPR<=128.
__global__ __launch_bounds__(TPB, 4) void fused_kernel(const float* __restrict__ unif,
                                                       const vf4* __restrict__ pr4,
                                                       const vf4* __restrict__ wd4,
                                                       float* __restrict__ out) {
  __shared__ uint64_t sPos[NCHP];    // contiguous positivity bits
  __shared__ uint64_t sKeep[NCHP];   // phase A: ballot staging; D/F: keep bits
  __shared__ uint64_t sLv[4];        // live = R & O

  const int tid  = threadIdx.x;
  const int lane = tid & 63;
  const int wv   = tid >> 6;
  const int row  = blockIdx.x;
  const vf4* up4 = (const vf4*)(unif + (size_t)row * PTOT);
  vf4*       op4 = (vf4*)(out + (size_t)row * PTOT);

  vf4 mv[NITER];                     // per-thread registered m values

  // ---- Phase A: stream u -> m (registers) + ballot (2-deep pipeline) ------
  {
    vf4 u = {0.f,0.f,0.f,0.f}, p = {0.f,0.f,0.f,0.f}, w = {1.f,1.f,1.f,1.f};
    {
      int e4 = wv * 64 + lane;       // k=0: always in-bounds (G<=7)
      u = up4[e4]; p = pr4[e4]; w = wd4[e4];
    }
#pragma unroll
    for (int k = 0; k < NITER; ++k) {
      const int G = wv + k * NWV;
      const bool act = G < NGRP;                 // wave-uniform
      // issue next iteration's loads
      vf4 un = {0.f,0.f,0.f,0.f}, pn = {0.f,0.f,0.f,0.f}, wn = {1.f,1.f,1.f,1.f};
      if (k + 1 < NITER) {
        const int Gn = G + NWV;
        if (Gn < NGRP) {
          int e4n = Gn * 64 + lane;
          bool inbn = e4n < (PTOT / 4);
          un = inbn ? up4[e4n] : (vf4){0.f,0.f,0.f,0.f};
          pn = pr4[e4n]; wn = wd4[e4n];
        }
      }
      if (act) {
        int e4 = G * 64 + lane;
        bool inb = e4 < (PTOT / 4);
        float m0 = __fadd_rn(__fdiv_rn(__fsub_rn(p.x, u.x), w.x), 0.5f);
        float m1 = __fadd_rn(__fdiv_rn(__fsub_rn(p.y, u.y), w.y), 0.5f);
        float m2 = __fadd_rn(__fdiv_rn(__fsub_rn(p.z, u.z), w.z), 0.5f);
        float m3 = __fadd_rn(__fdiv_rn(__fsub_rn(p.w, u.w), w.w), 0.5f);
        mv[k] = (vf4){m0, m1, m2, m3};
        uint64_t b0 = __ballot(inb && (m0 > 0.0f));
        uint64_t b1 = __ballot(inb && (m1 > 0.0f));
        uint64_t b2 = __ballot(inb && (m2 > 0.0f));
        uint64_t b3 = __ballot(inb && (m3 > 0.0f));
        if (lane < 4) {
          uint64_t v = (lane == 0) ? b0 : (lane == 1) ? b1 : (lane == 2) ? b2 : b3;
          sKeep[G * 4 + lane] = v;
        }
      }
      u = un; p = pn; w = wn;
    }
  }
  __syncthreads();

  // ---- Phase B: deinterleave ballots -> contiguous-bit words; zero sKeep --
  for (int G = tid; G < NGRP; G += TPB) {
    uint64_t b0 = sKeep[4 * G], b1 = sKeep[4 * G + 1];
    uint64_t b2 = sKeep[4 * G + 2], b3 = sKeep[4 * G + 3];
#pragma unroll
    for (int q = 0; q < 4; ++q) {
      uint64_t v = spread4((b0 >> (16 * q)) & 0xFFFFull)
                 | (spread4((b1 >> (16 * q)) & 0xFFFFull) << 1)
                 | (spread4((b2 >> (16 * q)) & 0xFFFFull) << 2)
                 | (spread4((b3 >> (16 * q)) & 0xFFFFull) << 3);
      sPos[4 * G + q] = v;
      sKeep[4 * G + q] = 0ull;
    }
  }
  for (int w = BMW + tid; w < NCHP; w += TPB) { sPos[w] = 0ull; sKeep[w] = 0ull; }
  __syncthreads();

  // ---- Phase C: forward R then backward O on wave 0 -----------------------
  if (tid < 64) {
    uint64_t R0 = 3ull, R1 = 0ull, R2 = 0ull;
    const int g = lane;
#pragma unroll
    for (int L = 0; L < NL; ++L) {
      const int Vq = 2 + 13 * L;
      const int b  = c_base[L];
      bool pred = false;
      if (g < 36) {
        uint32_t off = (uint32_t)(b + g * Vq);
        uint64_t e0 = ext(sPos, off), e1 = ext(sPos, off + 64), e2 = ext(sPos, off + 128);
        pred = ((e0 & R0) | (e1 & R1) | (e2 & R2)) != 0ull;
      }
      uint64_t bal = __ballot(pred);
      uint64_t ar  = bal & (bal >> 12) & (bal >> 24) & 0xFFFull;
      orAt(R0, R1, R2, ar, (uint32_t)Vq);
      const int Vm = Vq + 12;
      uint32_t offm = (uint32_t)(b + 36 * Vq);
      uint64_t e0 = ext(sPos, offm), e1 = ext(sPos, offm + 64), e2 = ext(sPos, offm + 128);
      uint64_t mr = (((e0 & R0) | (e1 & R1) | (e2 & R2)) != 0ull) ? 1ull : 0ull;
      orAt(R0, R1, R2, mr, (uint32_t)Vm);
    }

    // backward liveness with on-the-fly R-masking (O ⊆ R)
    uint64_t O0 = ext(sPos, LMB)       & R0;
    uint64_t O1 = ext(sPos, LMB + 64)  & R1;
    uint64_t O2 = ext(sPos, LMB + 128) & ((1ull << 30) - 1ull) & R2;
    const int hg = g % 12;
#pragma unroll
    for (int L = NL - 1; L >= 0; --L) {
      const int Vq = 2 + 13 * L, Vm = Vq + 12;
      const int b  = c_base[L];
      if (rbit(O0, O1, O2, (uint32_t)Vm)) {
        uint64_t m0, m1, m2; maskLen((uint32_t)Vm, m0, m1, m2);
        uint32_t offm = (uint32_t)(b + 36 * Vq);
        O0 |= ext(sPos, offm)       & R0 & m0;
        O1 |= ext(sPos, offm + 64)  & R1 & m1;
        O2 |= ext(sPos, offm + 128) & R2 & m2;
      }
      uint32_t h12 = ext12(O0, O1, O2, (uint32_t)Vq);
      uint64_t q0, q1, q2; maskLen((uint32_t)Vq, q0, q1, q2);
      uint64_t c0 = 0ull, c1 = 0ull, c2 = 0ull;
      if (g < 36 && ((h12 >> hg) & 1u)) {
        uint32_t off = (uint32_t)(b + g * Vq);
        c0 = ext(sPos, off)       & R0 & q0;
        c1 = ext(sPos, off + 64)  & R1 & q1;
        c2 = ext(sPos, off + 128) & R2 & q2;
      }
#pragma unroll
      for (int d = 32; d; d >>= 1) {
        c0 |= __shfl_xor((unsigned long long)c0, d);
        c1 |= __shfl_xor((unsigned long long)c1, d);
        c2 |= __shfl_xor((unsigned long long)c2, d);
      }
      O0 |= c0; O1 |= c1; O2 |= c2;
    }
    if (lane == 0) {
      sLv[0] = R0 & O0; sLv[1] = R1 & O1; sLv[2] = R2 & O2; sLv[3] = 0ull;
    }
  }
  __syncthreads();

  // ---- Phase D: build keep bitvector via shifted live windows -------------
  {
    const uint64_t l0 = sLv[0], l1 = sLv[1], l2 = sLv[2];
    for (int s = tid; s < NSEG; s += TPB) {
      uint32_t p0, len;
      bool olive;
      if (s == NSEG - 1) {               // LM tail: keep[i] = live[i]
        p0 = LMB; len = 158; olive = true;
      } else {
        int L = s / 37, j = s - L * 37;
        int Vq = 2 + 13 * L, b = c_base[L];
        if (j < 36) { p0 = (uint32_t)(b + j * Vq); len = (uint32_t)Vq;
                      olive = rbit(l0, l1, l2, (uint32_t)(Vq + (j % 12))) != 0ull; }
        else        { p0 = (uint32_t)(b + 36 * Vq); len = (uint32_t)(Vq + 12);
                      olive = rbit(l0, l1, l2, (uint32_t)(Vq + 12)) != 0ull; }
      }
      if (!olive) continue;
      uint32_t w0 = p0 >> 6, s0 = p0 & 63;
      uint64_t first = l0;
      if (len < 64) first &= (1ull << len) - 1ull;
      atomicOr((unsigned long long*)&sKeep[w0], (unsigned long long)(first << s0));
      uint32_t done = 64 - s0;
      uint32_t w = w0 + 1;
      while (done < len) {
        uint64_t v = rext(l0, l1, l2, done);
        uint32_t rem = len - done;
        if (rem < 64) v &= (1ull << rem) - 1ull;
        atomicOr((unsigned long long*)&sKeep[w], (unsigned long long)v);
        done += 64; ++w;
      }
    }
  }
  __syncthreads();

  // ---- Phase F: apply keep to registered m + single streaming store -------
  // Param index of lane's element c: P = G*256 + 4*lane + c
  //   -> keep word G*4 + (lane>>4), bits 4*(lane&15)+c (nibble per lane).
  {
    const int sh = 4 * (lane & 15);
    const int kw0 = lane >> 4;
#pragma unroll
    for (int k = 0; k < NITER; ++k) {
      const int G = wv + k * NWV;
      if (G >= NGRP) continue;                   // wave-uniform
      int e4 = G * 64 + lane;
      bool inb = e4 < (PTOT / 4);
      uint32_t kb = (uint32_t)(sKeep[G * 4 + kw0] >> sh) & 0xFu;
      vf4 m = mv[k];
      if (inb) {
        vf4 o;
        o.x = (kb & 1u) ? fminf(fmaxf(m.x, 0.0f), 1.0f) : 0.0f;
        o.y = (kb & 2u) ? fminf(fmaxf(m.y, 0.0f), 1.0f) : 0.0f;
        o.z = (kb & 4u) ? fminf(fmaxf(m.z, 0.0f), 1.0f) : 0.0f;
        o.w = (kb & 8u) ? fminf(fmaxf(m.w, 0.0f), 1.0f) : 0.0f;
        __builtin_nontemporal_store(o, &op4[e4]);
      }
    }
  }
}

extern "C" void kernel_launch(void* const* d_in, const int* in_sizes, int n_in,
                              void* d_out, int out_size, void* d_ws, size_t ws_size,
                              hipStream_t stream) {
  const float* sp   = (const float*)d_in[0];
  const float* unif = (const float*)d_in[1];
  float* out = (float*)d_out;
  char* ws = (char*)d_ws;
  float* pr = (float*)ws;                                  // 132096 B
  float* wd = (float*)(ws + 132096);                       // 132096 B
  int bz = in_sizes[1] / PTOT;   // 1024

  init_tables<<<dim3(TPAD / 256), dim3(256), 0, stream>>>(sp, pr, wd);
  fused_kernel<<<dim3(bz), dim3(TPB), 0, stream>>>(
      unif, (const vf4*)pr, (const vf4*)wd, out);
}